// Round 11
// baseline (283.867 us; speedup 1.0000x reference)
//
#include <hip/hip_runtime.h>
#include <hip/hip_fp16.h>
#include <stdint.h>

#define N_PRO 60000
#define N_WAT 40000
#define NN    100000
#define NNP   100032            // padded to a multiple of 64 for tiles
#define NE    1000000
#define IN_DIM 21
#define HID    32
#define HEADS  4
#define HC     128
#define EDGE_K 32
#define LUTN   2048             // distance-LUT bins, bin = dist*256 (range [0,8))
#define NH0B  ((NNP * 32) / 256)       // h0 blocks
#define NBUCK 392                      // coarse buckets of 256 nodes (node>>8)
#define BSH   8                        // bucket shift
#define BMSK  255                      // in-bucket node mask
#define EPT   8                        // edges per thread in scat
#define SCATB ((NE / EPT + 255) / 256) // 489 blocks
#define FCAP  3072                     // per-bucket region capacity (mean 2551 + 10 sigma)
#define SLOTS (NBUCK * FCAP)           // 1,204,224 region-addressed slots (unchanged)
#define GSTRIDE 16                     // gcur padding: 1 counter per 64B line

typedef _Float16 half8 __attribute__((ext_vector_type(8)));
typedef float    f32x4 __attribute__((ext_vector_type(4)));

// ---------------------------------------------------------------------------
// K0 (k_pre, 17 blocks): block 16 = tiny fused weights (smallw) + W1->fp16
// pack (w1h) + gcur zero (padded). Blocks 0..15 = distance LUT.
// smallw floats: [0..127]=U1, [128..131]=aeb1, [132..259]=U2, [260..263]=aeb2,
// [264..295]=h0w, [296..423]=va_s1, [424..551]=va_d1
// ---------------------------------------------------------------------------
__global__ __launch_bounds__(256) void k_pre(
    const float* We, const float* be,
    const float* Wedge1, const float* atte1,
    const float* Wedge2, const float* atte2,
    const float* Wf, const float* bfv,
    const float* W1, const float* atts1, const float* attd1,
    const float* gamma,
    float* smallw, float* lut, __half* w1h, int* gcur)
{
    __shared__ float V[2][128];
    __shared__ float aebs[4];
    int t = threadIdx.x;
    if (blockIdx.x == 16) {
        {
            int l = t >> 7, dh = t & 127, d = dh >> 2, h = dh & 3;
            const float* Wg = l ? Wedge2 : Wedge1;
            const float* ae = l ? atte2 : atte1;
            float s = 0.f;
            for (int c = 0; c < HID; c++)
                s += Wg[d * HC + h * HID + c] * ae[h * HID + c];
            V[l][dh] = s;
        }
        __syncthreads();
        {
            int l = t >> 7, kh = t & 127, k = kh >> 2, h = kh & 3;
            float s = 0.f;
            for (int d = 0; d < 32; d++)
                s += We[k * 32 + d] * V[l][d * 4 + h];
            smallw[(l ? 132 : 0) + kh] = s;
        }
        if (t < 8) {
            int l = t >> 2, h = t & 3;
            float s = 0.f;
            for (int d = 0; d < 32; d++)
                s += be[d] * V[l][d * 4 + h];
            smallw[(l ? 260 : 128) + h] = s;
        }
        if (t >= 32 && t < 64) {
            int c = t - 32;
            smallw[264 + c] = Wf[20 * 32 + c] + bfv[c];
        }
        {
            int side = t >> 7;
            int h = (t >> 5) & 3, c = t & 31;
            const float* av = side ? attd1 : atts1;
            float s = 0.f;
            for (int j = 0; j < 32; j++)
                s += W1[c * 128 + h * 32 + j] * av[h * 32 + j];
            smallw[(side ? 424 : 296) + (t & 127)] = s;
        }
        // W1 -> fp16, k_zm Wt layout [c*40 + k], 80B rows
        for (int i = t; i < 128 * 8; i += 256) {
            int c = i & 127, k4 = (i >> 7) * 4;
            float w0 = W1[(k4 + 0) * 128 + c];
            float w1v = W1[(k4 + 1) * 128 + c];
            float w2 = W1[(k4 + 2) * 128 + c];
            float w3 = W1[(k4 + 3) * 128 + c];
            __half2 p0 = __floats2half2_rn(w0, w1v);
            __half2 p1 = __floats2half2_rn(w2, w3);
            uint2 pk;
            pk.x = *(unsigned*)&p0;
            pk.y = *(unsigned*)&p1;
            *(uint2*)&w1h[c * 40 + k4] = pk;
        }
        for (int i = t; i < NBUCK * GSTRIDE; i += 256) gcur[i] = 0;
        return;
    }
    // LUT blocks: 256 entries each; layer uniform per block.
    int e = blockIdx.x * 256 + t;
    int layer = e >> 11, bin = e & (LUTN - 1);
    const float* Wg = layer ? Wedge2 : Wedge1;
    const float* ae = layer ? atte2 : atte1;
    if (t < 128) {
        int d = t >> 2, h = t & 3;
        float s = 0.f;
        for (int c = 0; c < 32; c++)
            s += Wg[d * HC + h * HID + c] * ae[h * HID + c];
        V[0][t] = s;
    }
    __syncthreads();
    if (t < 128) {
        int k = t >> 2, h = t & 3;
        float s = 0.f;
        for (int d = 0; d < 32; d++)
            s += We[k * 32 + d] * V[0][d * 4 + h];
        V[1][t] = s;
    }
    if (t >= 128 && t < 132) {
        int h = t - 128;
        float s = 0.f;
        for (int d = 0; d < 32; d++)
            s += be[d] * V[0][d * 4 + h];
        aebs[h] = s;
    }
    __syncthreads();
    const float* U = V[1];
    float dd = bin * (1.0f / 256.0f);
    float g = gamma[0];
    float a0 = aebs[0], a1 = aebs[1], a2 = aebs[2], a3 = aebs[3];
    const float step = 5.0f / 31.0f;
    #pragma unroll
    for (int k = 0; k < EDGE_K; k++) {
        float tt = dd - (float)k * step;
        float r = __expf(-g * tt * tt);
        a0 += r * U[k * 4 + 0];
        a1 += r * U[k * 4 + 1];
        a2 += r * U[k * 4 + 2];
        a3 += r * U[k * 4 + 3];
    }
    *(float4*)&lut[(size_t)e * 4] = make_float4(a0, a1, a2, a3);
}

// ---------------------------------------------------------------------------
// K2 (k_hs, MERGED, SCAT-FIRST): blocks < SCATB run the fixed-region bucket
// scatter (r8's direct-scatter form — the r10 counting sort was time-neutral
// but cost 20KB LDS and 22 points of occupancy). Buckets are now 256 nodes
// (d>>8, 392 of them): rank atomics spread over 392 LDS counters (fewer
// collisions); flush = 2 rounds of padded gcur atomics.
// Blocks >= SCATB run h0 = feats@Wf+bf (fp16) + layer-1 logits asd.
// ---------------------------------------------------------------------------
__global__ __launch_bounds__(256) void k_hs(
    const float* __restrict__ pf, const float* __restrict__ Wf,
    const float* __restrict__ bfv, const float* __restrict__ smallw,
    const int* __restrict__ ei, const float* __restrict__ ppos,
    const float* __restrict__ wpos, int* __restrict__ gcur,
    uint2* __restrict__ ebuf2,
    __half* __restrict__ h0, float* __restrict__ asd)
{
    int t = threadIdx.x;
    if (blockIdx.x < SCATB) {
        // ---- scat half (issued first => co-resident with h0 stream) ----
        __shared__ int lh[NBUCK];
        __shared__ int lbase[NBUCK];
        for (int b = t; b < NBUCK; b += 256) lh[b] = 0;
        __syncthreads();
        int e0 = (blockIdx.x * 256 + t) * EPT;
        int bkt[EPT], rnk[EPT];
        unsigned rec0[EPT], rec1[EPT];
        #pragma unroll
        for (int j = 0; j < EPT; j++) bkt[j] = -1;
        if (e0 < NE) {                   // NE % EPT == 0 -> full int4 ok
            int4 sa = *(const int4*)&ei[e0];
            int4 sb = *(const int4*)&ei[e0 + 4];
            int4 da = *(const int4*)&ei[NE + e0];
            int4 db = *(const int4*)&ei[NE + e0 + 4];
            int ss[8] = {sa.x, sa.y, sa.z, sa.w, sb.x, sb.y, sb.z, sb.w};
            int ds[8] = {da.x, da.y, da.z, da.w, db.x, db.y, db.z, db.w};
            #pragma unroll
            for (int j = 0; j < EPT; j++) {
                int s = ss[j], d = ds[j];
                if ((unsigned)d < (unsigned)NN) {
                    const float* ps = (s < N_PRO) ? &ppos[s * 3] : &wpos[(s - N_PRO) * 3];
                    const float* pd = (d < N_PRO) ? &ppos[d * 3] : &wpos[(d - N_PRO) * 3];
                    float dx = pd[0] - ps[0];
                    float dy = pd[1] - ps[1];
                    float dz = pd[2] - ps[2];
                    float dist = sqrtf(dx * dx + dy * dy + dz * dz);
                    unsigned code = (unsigned)fminf(dist * 4096.0f, 32767.0f);
                    bkt[j] = d >> BSH;
                    rec0[j] = ((unsigned)d << 15) | code;
                    rec1[j] = (unsigned)s;
                    rnk[j] = atomicAdd(&lh[bkt[j]], 1);
                }
            }
        }
        __syncthreads();
        for (int b = t; b < NBUCK; b += 256)
            lbase[b] = lh[b] ? atomicAdd(&gcur[b * GSTRIDE], lh[b]) : 0;
        __syncthreads();
        #pragma unroll
        for (int j = 0; j < EPT; j++)
            if (bkt[j] >= 0) {
                int p = lbase[bkt[j]] + rnk[j];
                if (p < FCAP)   // ~10-sigma overflow guard
                    ebuf2[(size_t)bkt[j] * FCAP + p] = make_uint2(rec0[j], rec1[j]);
            }
        return;
    }
    // ---- h0 half ----
    __shared__ float Wfs[IN_DIM * 32];
    __shared__ float bfs[32];
    __shared__ float h0w[32];
    __shared__ float vas[128], vad[128];
    for (int i = t; i < IN_DIM * 32; i += 256) Wfs[i] = Wf[i];
    if (t < 32) { bfs[t] = bfv[t]; h0w[t] = smallw[264 + t]; }
    if (t < 128) vas[t] = smallw[296 + t];
    else         vad[t - 128] = smallw[424 + (t - 128)];
    __syncthreads();
    int id = (blockIdx.x - SCATB) * 256 + t;
    int n = id >> 5, c = id & 31;
    if (n >= NNP) return;
    float v;
    if (n < N_PRO) {
        float s = bfs[c];
        for (int k = 0; k < IN_DIM; k++)
            s += pf[n * IN_DIM + k] * Wfs[k * 32 + c];
        v = s;
    } else {
        v = h0w[c];
    }
    h0[(size_t)n * 32 + c] = __float2half(v);
    float ps[4], pd[4];
    #pragma unroll
    for (int h = 0; h < 4; h++) {
        ps[h] = v * vas[h * 32 + c];
        pd[h] = v * vad[h * 32 + c];
    }
    #pragma unroll
    for (int m = 1; m < 32; m <<= 1) {
        #pragma unroll
        for (int h = 0; h < 4; h++) {
            ps[h] += __shfl_xor(ps[h], m, 64);
            pd[h] += __shfl_xor(pd[h], m, 64);
        }
    }
    if ((t & 31) == 0) {
        *(float4*)&asd[(size_t)n * 8]     = make_float4(ps[0], ps[1], ps[2], ps[3]);
        *(float4*)&asd[(size_t)n * 8 + 4] = make_float4(pd[0], pd[1], pd[2], pd[3]);
    }
}

// ---------------------------------------------------------------------------
// k_fine: one block per 256-node bucket, 512 threads, 26KB LDS — 392 blocks
// now cover every CU (the 196-block version left 60 CUs idle). LDS staging,
// fine-count, wave-shuffle scan, GLOBAL offA/offE, then place e4 + exp'd
// layer-1 wb.
// ---------------------------------------------------------------------------
__global__ __launch_bounds__(512) void k_fine(
    const int* __restrict__ gcur, const uint2* __restrict__ ebuf2,
    const float* __restrict__ lutg, const float* __restrict__ asd,
    int* __restrict__ offA, int* __restrict__ offE,
    unsigned* __restrict__ e4, float* __restrict__ wb)
{
    __shared__ uint2 eL[FCAP];          // 24 KB
    __shared__ int lcnt[256], lexc[256];
    __shared__ int wsum[4];
    int b = blockIdx.x, t = threadIdx.x;
    int beg = b * FCAP;
    int nb = gcur[b * GSTRIDE];
    if (nb > FCAP) nb = FCAP;
    for (int i = t; i < nb; i += 512) eL[i] = ebuf2[beg + i];
    if (t < 256) lcnt[t] = 0;
    __syncthreads();
    for (int i = t; i < nb; i += 512)
        atomicAdd(&lcnt[(eL[i].x >> 15) & BMSK], 1);
    __syncthreads();
    int c = 0;
    if (t < 256) {                       // waves 0..3 fully active
        c = lcnt[t];
        int lane = t & 63;
        int v = c;
        #pragma unroll
        for (int d = 1; d < 64; d <<= 1) {
            int x = __shfl_up(v, d, 64);
            if (lane >= d) v += x;
        }
        if (lane == 63) wsum[t >> 6] = v;
        lexc[t] = v - c;                 // wave-local exclusive prefix
    }
    __syncthreads();
    if (t == 0) {                        // exclusive scan of 4 wave sums
        int s = 0;
        #pragma unroll
        for (int k = 0; k < 4; k++) { int x = wsum[k]; wsum[k] = s; s += x; }
    }
    __syncthreads();
    if (t < 256) {
        lexc[t] += wsum[t >> 6];
        int node = (b << BSH) + t;
        if (node < NN) {
            offA[node] = beg + lexc[t];
            offE[node] = beg + lexc[t] + c;
        }
        lcnt[t] = 0;                     // reuse as per-node cursor
    }
    __syncthreads();
    for (int i = t; i < nb; i += 512) {
        uint2 u = eL[i];
        int ln = (int)((u.x >> 15) & BMSK);
        int r = atomicAdd(&lcnt[ln], 1);
        int p = beg + lexc[ln] + r;
        unsigned code = u.x & 32767u;
        unsigned s = u.y;
        e4[p] = (s << 15) | code;
        int n = (b << BSH) + ln;
        float f = fminf((float)code * 0.0625f, (float)(LUTN - 2));
        int i0 = (int)f;
        float fr = f - (float)i0;
        float4 A = *(const float4*)&lutg[(size_t)i0 * 4];
        float4 B = *(const float4*)&lutg[(size_t)(i0 + 1) * 4];
        float4 as4 = *(const float4*)&asd[(size_t)s * 8];
        float4 ad4 = *(const float4*)&asd[(size_t)n * 8 + 4];
        float v0 = as4.x + ad4.x + A.x + (B.x - A.x) * fr;
        float v1 = as4.y + ad4.y + A.y + (B.y - A.y) * fr;
        float v2 = as4.z + ad4.z + A.z + (B.z - A.z) * fr;
        float v3 = as4.w + ad4.w + A.w + (B.w - A.w) * fr;
        v0 = fmaxf(v0, 0.2f * v0);
        v1 = fmaxf(v1, 0.2f * v1);
        v2 = fmaxf(v2, 0.2f * v2);
        v3 = fmaxf(v3, 0.2f * v3);
        *(float4*)&wb[(size_t)p * 4] = make_float4(
            __expf(v0), __expf(v1), __expf(v2), __expf(v3));
    }
}

// ---------------------------------------------------------------------------
// K6 (MFMA): x = hbuf @ W2 (+ logits) via mfma_f32_16x16x32_f16.
// ---------------------------------------------------------------------------
__global__ __launch_bounds__(256) void k_xm(
    const __half* __restrict__ h, const float* __restrict__ Wg,
    const float* __restrict__ atts, const float* __restrict__ attd,
    __half* __restrict__ x16, float* __restrict__ asd)
{
    __shared__ __half Wt[128 * 136];
    __shared__ float attS[128], attD[128];
    int t = threadIdx.x;
    for (int i = t; i < 128 * 32; i += 256) {
        int c = i & 127, d = (i >> 7) * 4;
        float w0 = Wg[(d + 0) * 128 + c];
        float w1 = Wg[(d + 1) * 128 + c];
        float w2 = Wg[(d + 2) * 128 + c];
        float w3 = Wg[(d + 3) * 128 + c];
        __half2 p0 = __floats2half2_rn(w0, w1);
        __half2 p1 = __floats2half2_rn(w2, w3);
        uint2 pk;
        pk.x = *(unsigned*)&p0;
        pk.y = *(unsigned*)&p1;
        *(uint2*)&Wt[c * 136 + d] = pk;
    }
    if (t < 128) { attS[t] = atts[t]; attD[t] = attd[t]; }
    __syncthreads();
    int wv = t >> 6, lane = t & 63;
    int m16 = lane & 15, quad = lane >> 4;
    int n0 = blockIdx.x * 64 + wv * 16;
    f32x4 acc[8];
    #pragma unroll
    for (int ct = 0; ct < 8; ct++) acc[ct] = (f32x4){0.f, 0.f, 0.f, 0.f};
    #pragma unroll
    for (int ks = 0; ks < 4; ks++) {
        int d0 = ks * 32 + quad * 8;
        half8 bf = *(const half8*)&h[(size_t)(n0 + m16) * 128 + d0];
        #pragma unroll
        for (int ct = 0; ct < 8; ct++) {
            half8 af = *(const half8*)&Wt[(ct * 16 + m16) * 136 + d0];
            acc[ct] = __builtin_amdgcn_mfma_f32_16x16x32_f16(af, bf, acc[ct], 0, 0, 0);
        }
    }
    __half* xrow = &x16[(size_t)(n0 + m16) * 128 + quad * 4];
    float ps[4] = {0.f, 0.f, 0.f, 0.f}, pd[4] = {0.f, 0.f, 0.f, 0.f};
    #pragma unroll
    for (int ct = 0; ct < 8; ct++) {
        f32x4 a = acc[ct];
        __half2 h0p = __floats2half2_rn(a[0], a[1]);
        __half2 h1p = __floats2half2_rn(a[2], a[3]);
        uint2 pk;
        pk.x = *(unsigned*)&h0p;
        pk.y = *(unsigned*)&h1p;
        *(uint2*)&xrow[ct * 16] = pk;
        int cb = ct * 16 + quad * 4;
        int hh = ct >> 1;
        ps[hh] += a[0] * attS[cb] + a[1] * attS[cb + 1]
                + a[2] * attS[cb + 2] + a[3] * attS[cb + 3];
        pd[hh] += a[0] * attD[cb] + a[1] * attD[cb + 1]
                + a[2] * attD[cb + 2] + a[3] * attD[cb + 3];
    }
    #pragma unroll
    for (int hh = 0; hh < 4; hh++) {
        ps[hh] += __shfl_xor(ps[hh], 16, 64);
        ps[hh] += __shfl_xor(ps[hh], 32, 64);
        pd[hh] += __shfl_xor(pd[hh], 16, 64);
        pd[hh] += __shfl_xor(pd[hh], 32, 64);
    }
    if (lane < 16) {
        int n = n0 + m16;
        *(float4*)&asd[(size_t)n * 8]     = make_float4(ps[0], ps[1], ps[2], ps[3]);
        *(float4*)&asd[(size_t)n * 8 + 4] = make_float4(pd[0], pd[1], pd[2], pd[3]);
    }
}

// ---------------------------------------------------------------------------
// K8a (k_zm FUSED): layer-1 aggregation (16-lane group/node, unroll 4) THEN
// the blockdiag-W1 MFMA in the same block (zs LDS tile + k_zm epilogue).
// ---------------------------------------------------------------------------
__global__ __launch_bounds__(256) void k_aggz(
    const int* __restrict__ offA, const int* __restrict__ offE,
    const unsigned* __restrict__ e4, const float* __restrict__ wb,
    const __half* __restrict__ h016, const __half* __restrict__ w1h,
    const float* __restrict__ b1, __half* __restrict__ hbuf)
{
    __shared__ __half Wt[128 * 40];     // 10240 B, [c*40+k]
    __shared__ __half zs[16][136];      // 4352 B, padded rows
    int t = threadIdx.x;
    {
        uint4* dst = (uint4*)Wt;
        const uint4* src = (const uint4*)w1h;
        for (int i = t; i < 640; i += 256) dst[i] = src[i];
    }
    int wv = t >> 6, lane = t & 63;
    int g = lane >> 4, q = lane & 15;
    int n = blockIdx.x * 16 + wv * 4 + g;        // grid exact: NN/16
    int beg = offA[n], end = offE[n];
    const __half2* x2 = (const __half2*)h016;
    float a0x = 0.f, a0y = 0.f, a1x = 0.f, a1y = 0.f;
    float a2x = 0.f, a2y = 0.f, a3x = 0.f, a3y = 0.f;
    float l0 = 0.f, l1 = 0.f, l2 = 0.f, l3 = 0.f;
    int i = beg;
    for (; i + 3 < end; i += 4) {
        unsigned u0 = e4[i],     u1 = e4[i + 1];
        unsigned u2 = e4[i + 2], u3 = e4[i + 3];
        float4 w0 = *(const float4*)&wb[(size_t)i * 4];
        float4 w1 = *(const float4*)&wb[(size_t)(i + 1) * 4];
        float4 w2 = *(const float4*)&wb[(size_t)(i + 2) * 4];
        float4 w3 = *(const float4*)&wb[(size_t)(i + 3) * 4];
        float2 x0 = __half22float2(x2[(u0 >> 15) * 16u + q]);
        float2 x1 = __half22float2(x2[(u1 >> 15) * 16u + q]);
        float2 x2v = __half22float2(x2[(u2 >> 15) * 16u + q]);
        float2 x3 = __half22float2(x2[(u3 >> 15) * 16u + q]);
        a0x += w0.x * x0.x + w1.x * x1.x + w2.x * x2v.x + w3.x * x3.x;
        a0y += w0.x * x0.y + w1.x * x1.y + w2.x * x2v.y + w3.x * x3.y;
        a1x += w0.y * x0.x + w1.y * x1.x + w2.y * x2v.x + w3.y * x3.x;
        a1y += w0.y * x0.y + w1.y * x1.y + w2.y * x2v.y + w3.y * x3.y;
        a2x += w0.z * x0.x + w1.z * x1.x + w2.z * x2v.x + w3.z * x3.x;
        a2y += w0.z * x0.y + w1.z * x1.y + w2.z * x2v.y + w3.z * x3.y;
        a3x += w0.w * x0.x + w1.w * x1.x + w2.w * x2v.x + w3.w * x3.x;
        a3y += w0.w * x0.y + w1.w * x1.y + w2.w * x2v.y + w3.w * x3.y;
        l0 += (w0.x + w1.x) + (w2.x + w3.x);
        l1 += (w0.y + w1.y) + (w2.y + w3.y);
        l2 += (w0.z + w1.z) + (w2.z + w3.z);
        l3 += (w0.w + w1.w) + (w2.w + w3.w);
    }
    for (; i < end; i++) {
        unsigned u0 = e4[i];
        float4 w0 = *(const float4*)&wb[(size_t)i * 4];
        float2 x0 = __half22float2(x2[(u0 >> 15) * 16u + q]);
        a0x += w0.x * x0.x;  a0y += w0.x * x0.y;
        a1x += w0.y * x0.x;  a1y += w0.y * x0.y;
        a2x += w0.z * x0.x;  a2y += w0.z * x0.y;
        a3x += w0.w * x0.x;  a3y += w0.w * x0.y;
        l0 += w0.x; l1 += w0.y; l2 += w0.z; l3 += w0.w;
    }
    float i0v = 1.0f / (l0 + 1e-16f);
    float i1v = 1.0f / (l1 + 1e-16f);
    float i2v = 1.0f / (l2 + 1e-16f);
    float i3v = 1.0f / (l3 + 1e-16f);
    int nl = wv * 4 + g;
    *(__half2*)&zs[nl][     q * 2] = __floats2half2_rn(a0x * i0v, a0y * i0v);
    *(__half2*)&zs[nl][32 + q * 2] = __floats2half2_rn(a1x * i1v, a1y * i1v);
    *(__half2*)&zs[nl][64 + q * 2] = __floats2half2_rn(a2x * i2v, a2y * i2v);
    *(__half2*)&zs[nl][96 + q * 2] = __floats2half2_rn(a3x * i3v, a3y * i3v);
    __syncthreads();
    // MFMA: wave wv owns col-tiles {2wv, 2wv+1} (head wv) for all 16 rows.
    int m16 = lane & 15, quad = lane >> 4;
    half8 bf = *(const half8*)&zs[m16][wv * 32 + quad * 8];
    __half* orow = &hbuf[(size_t)(blockIdx.x * 16 + m16) * 128 + quad * 4];
    #pragma unroll
    for (int c2 = 0; c2 < 2; c2++) {
        int ct = wv * 2 + c2;
        half8 af = *(const half8*)&Wt[(ct * 16 + m16) * 40 + quad * 8];
        f32x4 acc = __builtin_amdgcn_mfma_f32_16x16x32_f16(
            af, bf, (f32x4){0.f, 0.f, 0.f, 0.f}, 0, 0, 0);
        int cb = ct * 16 + quad * 4;
        float4 bb = *(const float4*)&b1[cb];
        float r0 = acc[0] + bb.x;
        float r1 = acc[1] + bb.y;
        float r2 = acc[2] + bb.z;
        float r3 = acc[3] + bb.w;
        r0 = r0 > 0.f ? r0 : __expf(r0) - 1.0f;
        r1 = r1 > 0.f ? r1 : __expf(r1) - 1.0f;
        r2 = r2 > 0.f ? r2 : __expf(r2) - 1.0f;
        r3 = r3 > 0.f ? r3 : __expf(r3) - 1.0f;
        __half2 ha = __floats2half2_rn(r0, r1);
        __half2 hb = __floats2half2_rn(r2, r3);
        uint2 pk;
        pk.x = *(unsigned*)&ha;
        pk.y = *(unsigned*)&hb;
        *(uint2*)&orow[ct * 16] = pk;
    }
}

// ---------------------------------------------------------------------------
// K8b: layer-2 aggregation with INLINE weight computation, UNROLL 4.
// 32-lane group per node.
// ---------------------------------------------------------------------------
__global__ __launch_bounds__(256) void k_agg2(
    const int* __restrict__ offA, const int* __restrict__ offE,
    const unsigned* __restrict__ e4,
    const float* __restrict__ lutg, const float* __restrict__ asd,
    const __half* __restrict__ x16, const float* __restrict__ bias,
    __half* __restrict__ hout)
{
    int t = threadIdx.x;
    int wv = t >> 6, lane = t & 63;
    int g = lane >> 5, q = lane & 31;
    int n = N_PRO + blockIdx.x * 8 + wv * 2 + g;  // grid exact: N_WAT/8
    int h = q >> 3;
    int beg = offA[n], end = offE[n];
    float adh = asd[(size_t)n * 8 + 4 + h];
    float ax = 0.f, ay = 0.f, az = 0.f, aw = 0.f, ls = 0.f;
    int i = beg;
    for (; i + 3 < end; i += 4) {
        unsigned uu[4];
        float ww[4];
        float2 rr[4];
        #pragma unroll
        for (int j = 0; j < 4; j++) uu[j] = e4[i + j];
        #pragma unroll
        for (int j = 0; j < 4; j++) {
            unsigned s = uu[j] >> 15;
            float f = fminf((float)(uu[j] & 32767u) * 0.0625f, (float)(LUTN - 2));
            int i0 = (int)f;
            float fr = f - (float)i0;
            float A = lutg[i0 * 4 + h], B = lutg[(i0 + 1) * 4 + h];
            float as0 = asd[(size_t)s * 8 + h];
            rr[j] = *(const float2*)&x16[(size_t)s * 128 + q * 4];
            float v = as0 + adh + A + (B - A) * fr;
            v = fmaxf(v, 0.2f * v);
            ww[j] = __expf(v);
        }
        #pragma unroll
        for (int j = 0; j < 4; j++) {
            float2 fa = __half22float2(*(__half2*)&rr[j].x);
            float2 fb = __half22float2(*(__half2*)&rr[j].y);
            ax += ww[j] * fa.x;
            ay += ww[j] * fa.y;
            az += ww[j] * fb.x;
            aw += ww[j] * fb.y;
            ls += ww[j];
        }
    }
    for (; i < end; i++) {
        unsigned u0 = e4[i];
        unsigned s0 = u0 >> 15;
        float f0 = fminf((float)(u0 & 32767u) * 0.0625f, (float)(LUTN - 2));
        int i00 = (int)f0;
        float fr0 = f0 - (float)i00;
        float A0 = lutg[i00 * 4 + h], B0 = lutg[(i00 + 1) * 4 + h];
        float as0 = asd[(size_t)s0 * 8 + h];
        float2 r0 = *(const float2*)&x16[(size_t)s0 * 128 + q * 4];
        float v0 = as0 + adh + A0 + (B0 - A0) * fr0;
        v0 = fmaxf(v0, 0.2f * v0);
        float w0 = __expf(v0);
        float2 f00 = __half22float2(*(__half2*)&r0.x);
        float2 f01 = __half22float2(*(__half2*)&r0.y);
        ax += w0 * f00.x; ay += w0 * f00.y;
        az += w0 * f01.x; aw += w0 * f01.y;
        ls += w0;
    }
    float inv = 1.0f / (ls + 1e-16f);
    float4 bb = *(const float4*)&bias[q * 4];
    float o0 = ax * inv + bb.x;
    float o1 = ay * inv + bb.y;
    float o2 = az * inv + bb.z;
    float o3 = aw * inv + bb.w;
    o0 = o0 > 0.f ? o0 : __expf(o0) - 1.0f;
    o1 = o1 > 0.f ? o1 : __expf(o1) - 1.0f;
    o2 = o2 > 0.f ? o2 : __expf(o2) - 1.0f;
    o3 = o3 > 0.f ? o3 : __expf(o3) - 1.0f;
    __half2 ha = __floats2half2_rn(o0, o1);
    __half2 hb = __floats2half2_rn(o2, o3);
    uint2 pk;
    pk.x = *(unsigned*)&ha;
    pk.y = *(unsigned*)&hb;
    *(uint2*)&hout[(size_t)n * 128 + q * 4] = pk;
}

// ---------------------------------------------------------------------------
// K9 (MFMA): water MLP, k_xm-structure. 64 nodes/block, Wm1^T fp16 in LDS,
// epilogue bias+ReLU then 128->2 layer-2 via per-lane dots + shuffle-reduce.
// ---------------------------------------------------------------------------
__global__ __launch_bounds__(256) void k_mlp(
    const __half* __restrict__ hh, const float* __restrict__ Wm1,
    const float* __restrict__ bm1, const float* __restrict__ Wm2,
    const float* __restrict__ bm2, float* __restrict__ out)
{
    __shared__ __half Wt[128 * 136];
    __shared__ float b1s[128];
    __shared__ float w2s[256];
    int t = threadIdx.x;
    for (int i = t; i < 128 * 32; i += 256) {
        int c = i & 127, d = (i >> 7) * 4;
        float w0 = Wm1[(d + 0) * 128 + c];
        float w1 = Wm1[(d + 1) * 128 + c];
        float w2 = Wm1[(d + 2) * 128 + c];
        float w3 = Wm1[(d + 3) * 128 + c];
        __half2 p0 = __floats2half2_rn(w0, w1);
        __half2 p1 = __floats2half2_rn(w2, w3);
        uint2 pk;
        pk.x = *(unsigned*)&p0;
        pk.y = *(unsigned*)&p1;
        *(uint2*)&Wt[c * 136 + d] = pk;
    }
    if (t < 128) b1s[t] = bm1[t];
    w2s[t] = Wm2[t];                       // 256 floats = [128][2]
    __syncthreads();
    int wv = t >> 6, lane = t & 63;
    int m16 = lane & 15, quad = lane >> 4;
    int n0 = blockIdx.x * 64 + wv * 16;    // water-local node base
    f32x4 acc[8];
    #pragma unroll
    for (int ct = 0; ct < 8; ct++) acc[ct] = (f32x4){0.f, 0.f, 0.f, 0.f};
    #pragma unroll
    for (int ks = 0; ks < 4; ks++) {
        int d0 = ks * 32 + quad * 8;
        half8 bf = *(const half8*)&hh[(size_t)(N_PRO + n0 + m16) * 128 + d0];
        #pragma unroll
        for (int ct = 0; ct < 8; ct++) {
            half8 af = *(const half8*)&Wt[(ct * 16 + m16) * 136 + d0];
            acc[ct] = __builtin_amdgcn_mfma_f32_16x16x32_f16(af, bf, acc[ct], 0, 0, 0);
        }
    }
    float p0 = 0.f, p1 = 0.f;
    #pragma unroll
    for (int ct = 0; ct < 8; ct++) {
        int cb = ct * 16 + quad * 4;
        float4 bb = *(const float4*)&b1s[cb];
        float r0 = fmaxf(acc[ct][0] + bb.x, 0.f);
        float r1 = fmaxf(acc[ct][1] + bb.y, 0.f);
        float r2 = fmaxf(acc[ct][2] + bb.z, 0.f);
        float r3 = fmaxf(acc[ct][3] + bb.w, 0.f);
        p0 += r0 * w2s[(cb + 0) * 2] + r1 * w2s[(cb + 1) * 2]
            + r2 * w2s[(cb + 2) * 2] + r3 * w2s[(cb + 3) * 2];
        p1 += r0 * w2s[(cb + 0) * 2 + 1] + r1 * w2s[(cb + 1) * 2 + 1]
            + r2 * w2s[(cb + 2) * 2 + 1] + r3 * w2s[(cb + 3) * 2 + 1];
    }
    p0 += __shfl_xor(p0, 16, 64);
    p0 += __shfl_xor(p0, 32, 64);
    p1 += __shfl_xor(p1, 16, 64);
    p1 += __shfl_xor(p1, 32, 64);
    if (lane < 16) {
        int wn = n0 + m16;
        *(float2*)&out[(size_t)wn * 2] = make_float2(p0 + bm2[0], p1 + bm2[1]);
    }
}

// ---------------------------------------------------------------------------
extern "C" void kernel_launch(void* const* d_in, const int* in_sizes, int n_in,
                              void* d_out, int out_size, void* d_ws, size_t ws_size,
                              hipStream_t stream)
{
    const float* ppos   = (const float*)d_in[0];
    const float* wpos   = (const float*)d_in[1];
    const float* pfeat  = (const float*)d_in[2];
    const int*   ei     = (const int*)d_in[3];
    const float* gamma  = (const float*)d_in[4];
    const float* Wf     = (const float*)d_in[5];
    const float* bfv    = (const float*)d_in[6];
    const float* We     = (const float*)d_in[7];
    const float* be     = (const float*)d_in[8];
    const float* W1     = (const float*)d_in[9];
    const float* atts1  = (const float*)d_in[10];
    const float* attd1  = (const float*)d_in[11];
    const float* Wedge1 = (const float*)d_in[12];
    const float* atte1  = (const float*)d_in[13];
    const float* b1     = (const float*)d_in[14];
    const float* W2     = (const float*)d_in[15];
    const float* atts2  = (const float*)d_in[16];
    const float* attd2  = (const float*)d_in[17];
    const float* Wedge2 = (const float*)d_in[18];
    const float* atte2  = (const float*)d_in[19];
    const float* b2     = (const float*)d_in[20];
    const float* Wm1    = (const float*)d_in[21];
    const float* bm1    = (const float*)d_in[22];
    const float* Wm2    = (const float*)d_in[23];
    const float* bm2    = (const float*)d_in[24];
    float* out = (float*)d_out;

    char* ws = (char*)d_ws;
    size_t o = 0;
    auto alloc = [&](size_t bytes) -> char* {
        char* p = ws + o;
        o += (bytes + 255) & ~(size_t)255;
        return p;
    };
    __half*   h0      = (__half*)alloc((size_t)NNP * 32 * 2);
    __half*   x16     = (__half*)alloc((size_t)NNP * 128 * 2);
    __half*   hbuf    = (__half*)alloc((size_t)NNP * 128 * 2);
    float*    asd     = (float*)alloc((size_t)NNP * 8 * 4);
    float*    wb      = (float*)alloc((size_t)SLOTS * 4 * 4);    // region-addressed
    int*      offA    = (int*)alloc((size_t)NN * 4);
    int*      offE    = (int*)alloc((size_t)NN * 4);
    unsigned* e4      = (unsigned*)alloc((size_t)SLOTS * 4);
    int*      gcur    = (int*)alloc((size_t)NBUCK * GSTRIDE * 4);
    float*    smallw  = (float*)alloc(4096);
    float*    lutbuf  = (float*)alloc((size_t)2 * LUTN * 4 * 4);
    __half*   w1h     = (__half*)alloc((size_t)128 * 40 * 2);
    // ebuf2 (9.6 MB) overlays hbuf (25.6 MB): written by k_hs (scat half),
    // last read by k_fine, strictly before hbuf's first write in k_aggz.
    uint2*    ebuf2   = (uint2*)hbuf;

    // 7 dispatches total.
    k_pre<<<17, 256, 0, stream>>>(We, be, Wedge1, atte1, Wedge2, atte2, Wf, bfv,
                                  W1, atts1, attd1, gamma,
                                  smallw, lutbuf, w1h, gcur);
    k_hs<<<NH0B + SCATB, 256, 0, stream>>>(pfeat, Wf, bfv, smallw, ei, ppos, wpos,
                                           gcur, ebuf2, h0, asd);
    k_fine<<<NBUCK, 512, 0, stream>>>(gcur, ebuf2, lutbuf, asd, offA, offE, e4, wb);
    k_aggz<<<NN / 16, 256, 0, stream>>>(offA, offE, e4, wb, h0, w1h, b1, hbuf);
    k_xm<<<NNP / 64, 256, 0, stream>>>(hbuf, W2, atts2, attd2, x16, asd);
    k_agg2<<<N_WAT / 8, 256, 0, stream>>>(offA, offE, e4,
                                          lutbuf + (size_t)LUTN * 4, asd, x16, b2, hbuf);
    k_mlp<<<N_WAT / 64, 256, 0, stream>>>(hbuf, Wm1, bm1, Wm2, bm2, out);
}

// Round 12
// 278.018 us; speedup vs baseline: 1.0210x; 1.0210x over previous
//
#include <hip/hip_runtime.h>
#include <hip/hip_fp16.h>
#include <stdint.h>

#define N_PRO 60000
#define N_WAT 40000
#define NN    100000
#define NNP   100032            // padded to a multiple of 64 for tiles
#define NE    1000000
#define IN_DIM 21
#define HID    32
#define HEADS  4
#define HC     128
#define EDGE_K 32
#define LUTN   2048             // distance-LUT bins, bin = dist*256 (range [0,8))
#define NBUCK 196                      // coarse buckets of 512 nodes (node>>9)
#define BSH   9
#define BMSK  511
#define EPT   8                        // edges per thread in scat
#define HSTH  512                      // k_hs block size (4096 edges/scat block)
#define SCATB ((NE + HSTH * EPT - 1) / (HSTH * EPT))   // 245 blocks
#define NH0B  ((NNP * 32) / HSTH)      // 6252 h0 blocks
#define FCAP  6144                     // per-bucket region capacity (edges)
#define SLOTS (NBUCK * FCAP)           // 1,204,224 region-addressed slots
#define GSTRIDE 16                     // gcur padding: 1 counter per 64B line

typedef _Float16 half8 __attribute__((ext_vector_type(8)));
typedef float    f32x4 __attribute__((ext_vector_type(4)));

// ---------------------------------------------------------------------------
// K0 (k_pre, 17 blocks): block 16 = tiny fused weights (smallw) + W1->fp16
// pack (w1h) + gcur zero (padded). Blocks 0..15 = distance LUT.
// smallw floats: [0..127]=U1, [128..131]=aeb1, [132..259]=U2, [260..263]=aeb2,
// [264..295]=h0w, [296..423]=va_s1, [424..551]=va_d1
// ---------------------------------------------------------------------------
__global__ __launch_bounds__(256) void k_pre(
    const float* We, const float* be,
    const float* Wedge1, const float* atte1,
    const float* Wedge2, const float* atte2,
    const float* Wf, const float* bfv,
    const float* W1, const float* atts1, const float* attd1,
    const float* gamma,
    float* smallw, float* lut, __half* w1h, int* gcur)
{
    __shared__ float V[2][128];
    __shared__ float aebs[4];
    int t = threadIdx.x;
    if (blockIdx.x == 16) {
        {
            int l = t >> 7, dh = t & 127, d = dh >> 2, h = dh & 3;
            const float* Wg = l ? Wedge2 : Wedge1;
            const float* ae = l ? atte2 : atte1;
            float s = 0.f;
            for (int c = 0; c < HID; c++)
                s += Wg[d * HC + h * HID + c] * ae[h * HID + c];
            V[l][dh] = s;
        }
        __syncthreads();
        {
            int l = t >> 7, kh = t & 127, k = kh >> 2, h = kh & 3;
            float s = 0.f;
            for (int d = 0; d < 32; d++)
                s += We[k * 32 + d] * V[l][d * 4 + h];
            smallw[(l ? 132 : 0) + kh] = s;
        }
        if (t < 8) {
            int l = t >> 2, h = t & 3;
            float s = 0.f;
            for (int d = 0; d < 32; d++)
                s += be[d] * V[l][d * 4 + h];
            smallw[(l ? 260 : 128) + h] = s;
        }
        if (t >= 32 && t < 64) {
            int c = t - 32;
            smallw[264 + c] = Wf[20 * 32 + c] + bfv[c];
        }
        {
            int side = t >> 7;
            int h = (t >> 5) & 3, c = t & 31;
            const float* av = side ? attd1 : atts1;
            float s = 0.f;
            for (int j = 0; j < 32; j++)
                s += W1[c * 128 + h * 32 + j] * av[h * 32 + j];
            smallw[(side ? 424 : 296) + (t & 127)] = s;
        }
        // W1 -> fp16, k_zm Wt layout [c*40 + k], 80B rows
        for (int i = t; i < 128 * 8; i += 256) {
            int c = i & 127, k4 = (i >> 7) * 4;
            float w0 = W1[(k4 + 0) * 128 + c];
            float w1v = W1[(k4 + 1) * 128 + c];
            float w2 = W1[(k4 + 2) * 128 + c];
            float w3 = W1[(k4 + 3) * 128 + c];
            __half2 p0 = __floats2half2_rn(w0, w1v);
            __half2 p1 = __floats2half2_rn(w2, w3);
            uint2 pk;
            pk.x = *(unsigned*)&p0;
            pk.y = *(unsigned*)&p1;
            *(uint2*)&w1h[c * 40 + k4] = pk;
        }
        for (int i = t; i < NBUCK * GSTRIDE; i += 256) gcur[i] = 0;
        return;
    }
    // LUT blocks: 256 entries each; layer uniform per block.
    int e = blockIdx.x * 256 + t;
    int layer = e >> 11, bin = e & (LUTN - 1);
    const float* Wg = layer ? Wedge2 : Wedge1;
    const float* ae = layer ? atte2 : atte1;
    if (t < 128) {
        int d = t >> 2, h = t & 3;
        float s = 0.f;
        for (int c = 0; c < 32; c++)
            s += Wg[d * HC + h * HID + c] * ae[h * HID + c];
        V[0][t] = s;
    }
    __syncthreads();
    if (t < 128) {
        int k = t >> 2, h = t & 3;
        float s = 0.f;
        for (int d = 0; d < 32; d++)
            s += We[k * 32 + d] * V[0][d * 4 + h];
        V[1][t] = s;
    }
    if (t >= 128 && t < 132) {
        int h = t - 128;
        float s = 0.f;
        for (int d = 0; d < 32; d++)
            s += be[d] * V[0][d * 4 + h];
        aebs[h] = s;
    }
    __syncthreads();
    const float* U = V[1];
    float dd = bin * (1.0f / 256.0f);
    float g = gamma[0];
    float a0 = aebs[0], a1 = aebs[1], a2 = aebs[2], a3 = aebs[3];
    const float step = 5.0f / 31.0f;
    #pragma unroll
    for (int k = 0; k < EDGE_K; k++) {
        float tt = dd - (float)k * step;
        float r = __expf(-g * tt * tt);
        a0 += r * U[k * 4 + 0];
        a1 += r * U[k * 4 + 1];
        a2 += r * U[k * 4 + 2];
        a3 += r * U[k * 4 + 3];
    }
    *(float4*)&lut[(size_t)e * 4] = make_float4(a0, a1, a2, a3);
}

// ---------------------------------------------------------------------------
// K2 (k_hs, MERGED, SCAT-FIRST, 512-THREAD BLOCKS): blocks < SCATB run the
// direct bucket scatter with 4096 edges/block — DOUBLE r8's per-bucket run
// length (~21 records ≈ 168B) to cut partial-line write amplification (the
// variable that tracked k_hs time across r8/r9/r11: 19.5/27.2/27.5 MB ->
// 50.5/58.5/55.0 us). Per-thread code identical to r8 (EPT=8, ~44 VGPR).
// Blocks >= SCATB run h0 = feats@Wf+bf (fp16) + layer-1 logits asd.
// ---------------------------------------------------------------------------
__global__ __launch_bounds__(HSTH) void k_hs(
    const float* __restrict__ pf, const float* __restrict__ Wf,
    const float* __restrict__ bfv, const float* __restrict__ smallw,
    const int* __restrict__ ei, const float* __restrict__ ppos,
    const float* __restrict__ wpos, int* __restrict__ gcur,
    uint2* __restrict__ ebuf2,
    __half* __restrict__ h0, float* __restrict__ asd)
{
    int t = threadIdx.x;
    if (blockIdx.x < SCATB) {
        // ---- scat half (issued first => co-resident with h0 stream) ----
        __shared__ int lh[NBUCK];
        __shared__ int lbase[NBUCK];
        for (int b = t; b < NBUCK; b += HSTH) lh[b] = 0;
        __syncthreads();
        int e0 = (blockIdx.x * HSTH + t) * EPT;
        int bkt[EPT], rnk[EPT];
        unsigned rec0[EPT], rec1[EPT];
        #pragma unroll
        for (int j = 0; j < EPT; j++) bkt[j] = -1;
        if (e0 < NE) {                   // NE % EPT == 0 -> full int4 ok
            int4 sa = *(const int4*)&ei[e0];
            int4 sb = *(const int4*)&ei[e0 + 4];
            int4 da = *(const int4*)&ei[NE + e0];
            int4 db = *(const int4*)&ei[NE + e0 + 4];
            int ss[8] = {sa.x, sa.y, sa.z, sa.w, sb.x, sb.y, sb.z, sb.w};
            int ds[8] = {da.x, da.y, da.z, da.w, db.x, db.y, db.z, db.w};
            #pragma unroll
            for (int j = 0; j < EPT; j++) {
                int s = ss[j], d = ds[j];
                if ((unsigned)d < (unsigned)NN) {
                    const float* ps = (s < N_PRO) ? &ppos[s * 3] : &wpos[(s - N_PRO) * 3];
                    const float* pd = (d < N_PRO) ? &ppos[d * 3] : &wpos[(d - N_PRO) * 3];
                    float dx = pd[0] - ps[0];
                    float dy = pd[1] - ps[1];
                    float dz = pd[2] - ps[2];
                    float dist = sqrtf(dx * dx + dy * dy + dz * dz);
                    unsigned code = (unsigned)fminf(dist * 4096.0f, 32767.0f);
                    bkt[j] = d >> BSH;
                    rec0[j] = ((unsigned)d << 15) | code;
                    rec1[j] = (unsigned)s;
                    rnk[j] = atomicAdd(&lh[bkt[j]], 1);
                }
            }
        }
        __syncthreads();
        for (int b = t; b < NBUCK; b += HSTH)
            lbase[b] = lh[b] ? atomicAdd(&gcur[b * GSTRIDE], lh[b]) : 0;
        __syncthreads();
        #pragma unroll
        for (int j = 0; j < EPT; j++)
            if (bkt[j] >= 0) {
                int p = lbase[bkt[j]] + rnk[j];
                if (p < FCAP)   // 14-sigma overflow guard
                    ebuf2[(size_t)bkt[j] * FCAP + p] = make_uint2(rec0[j], rec1[j]);
            }
        return;
    }
    // ---- h0 half (512 threads: 16 nodes x 32 channels per block) ----
    __shared__ float Wfs[IN_DIM * 32];
    __shared__ float bfs[32];
    __shared__ float h0w[32];
    __shared__ float vas[128], vad[128];
    for (int i = t; i < IN_DIM * 32; i += HSTH) Wfs[i] = Wf[i];
    if (t < 32) { bfs[t] = bfv[t]; h0w[t] = smallw[264 + t]; }
    if (t < 128) vas[t] = smallw[296 + t];
    else if (t < 256) vad[t - 128] = smallw[424 + (t - 128)];
    __syncthreads();
    int id = (blockIdx.x - SCATB) * HSTH + t;
    int n = id >> 5, c = id & 31;
    if (n >= NNP) return;
    float v;
    if (n < N_PRO) {
        float s = bfs[c];
        for (int k = 0; k < IN_DIM; k++)
            s += pf[n * IN_DIM + k] * Wfs[k * 32 + c];
        v = s;
    } else {
        v = h0w[c];
    }
    h0[(size_t)n * 32 + c] = __float2half(v);
    float ps[4], pd[4];
    #pragma unroll
    for (int h = 0; h < 4; h++) {
        ps[h] = v * vas[h * 32 + c];
        pd[h] = v * vad[h * 32 + c];
    }
    #pragma unroll
    for (int m = 1; m < 32; m <<= 1) {
        #pragma unroll
        for (int h = 0; h < 4; h++) {
            ps[h] += __shfl_xor(ps[h], m, 64);
            pd[h] += __shfl_xor(pd[h], m, 64);
        }
    }
    if ((t & 31) == 0) {
        *(float4*)&asd[(size_t)n * 8]     = make_float4(ps[0], ps[1], ps[2], ps[3]);
        *(float4*)&asd[(size_t)n * 8 + 4] = make_float4(pd[0], pd[1], pd[2], pd[3]);
    }
}

// ---------------------------------------------------------------------------
// k_fine: one block per 512-node bucket, 1024 threads (r8's proven form).
// nb from padded gcur. LDS staging, fine-count, wave-shuffle scan, GLOBAL
// offA/offE, then place e4 + exp'd layer-1 wb.
// ---------------------------------------------------------------------------
__global__ __launch_bounds__(1024) void k_fine(
    const int* __restrict__ gcur, const uint2* __restrict__ ebuf2,
    const float* __restrict__ lutg, const float* __restrict__ asd,
    int* __restrict__ offA, int* __restrict__ offE,
    unsigned* __restrict__ e4, float* __restrict__ wb)
{
    __shared__ uint2 eL[FCAP];          // 48 KB
    __shared__ int lcnt[512], lexc[512];
    __shared__ int wsum[8];
    int b = blockIdx.x, t = threadIdx.x;
    int beg = b * FCAP;
    int nb = gcur[b * GSTRIDE];
    if (nb > FCAP) nb = FCAP;
    for (int i = t; i < nb; i += 1024) eL[i] = ebuf2[beg + i];
    if (t < 512) lcnt[t] = 0;
    __syncthreads();
    for (int i = t; i < nb; i += 1024)
        atomicAdd(&lcnt[(eL[i].x >> 15) & BMSK], 1);
    __syncthreads();
    int c = 0;
    if (t < 512) {                       // waves 0..7 fully active
        c = lcnt[t];
        int lane = t & 63;
        int v = c;
        #pragma unroll
        for (int d = 1; d < 64; d <<= 1) {
            int x = __shfl_up(v, d, 64);
            if (lane >= d) v += x;
        }
        if (lane == 63) wsum[t >> 6] = v;
        lexc[t] = v - c;                 // wave-local exclusive prefix
    }
    __syncthreads();
    if (t < 8) {                         // exclusive scan of 8 wave sums
        int orig = wsum[t];
        int v = orig;
        #pragma unroll
        for (int d = 1; d < 8; d <<= 1) {
            int x = __shfl_up(v, d, 64);
            if (t >= d) v += x;
        }
        wsum[t] = v - orig;
    }
    __syncthreads();
    if (t < 512) {
        lexc[t] += wsum[t >> 6];
        int node = (b << BSH) + t;
        if (node < NN) {
            offA[node] = beg + lexc[t];
            offE[node] = beg + lexc[t] + c;
        }
        lcnt[t] = 0;                     // reuse as per-node cursor
    }
    __syncthreads();
    for (int i = t; i < nb; i += 1024) {
        uint2 u = eL[i];
        int ln = (int)((u.x >> 15) & BMSK);
        int r = atomicAdd(&lcnt[ln], 1);
        int p = beg + lexc[ln] + r;
        unsigned code = u.x & 32767u;
        unsigned s = u.y;
        e4[p] = (s << 15) | code;
        int n = (b << BSH) + ln;
        float f = fminf((float)code * 0.0625f, (float)(LUTN - 2));
        int i0 = (int)f;
        float fr = f - (float)i0;
        float4 A = *(const float4*)&lutg[(size_t)i0 * 4];
        float4 B = *(const float4*)&lutg[(size_t)(i0 + 1) * 4];
        float4 as4 = *(const float4*)&asd[(size_t)s * 8];
        float4 ad4 = *(const float4*)&asd[(size_t)n * 8 + 4];
        float v0 = as4.x + ad4.x + A.x + (B.x - A.x) * fr;
        float v1 = as4.y + ad4.y + A.y + (B.y - A.y) * fr;
        float v2 = as4.z + ad4.z + A.z + (B.z - A.z) * fr;
        float v3 = as4.w + ad4.w + A.w + (B.w - A.w) * fr;
        v0 = fmaxf(v0, 0.2f * v0);
        v1 = fmaxf(v1, 0.2f * v1);
        v2 = fmaxf(v2, 0.2f * v2);
        v3 = fmaxf(v3, 0.2f * v3);
        *(float4*)&wb[(size_t)p * 4] = make_float4(
            __expf(v0), __expf(v1), __expf(v2), __expf(v3));
    }
}

// ---------------------------------------------------------------------------
// K6 (MFMA): x = hbuf @ W2 (+ logits) via mfma_f32_16x16x32_f16.
// ---------------------------------------------------------------------------
__global__ __launch_bounds__(256) void k_xm(
    const __half* __restrict__ h, const float* __restrict__ Wg,
    const float* __restrict__ atts, const float* __restrict__ attd,
    __half* __restrict__ x16, float* __restrict__ asd)
{
    __shared__ __half Wt[128 * 136];
    __shared__ float attS[128], attD[128];
    int t = threadIdx.x;
    for (int i = t; i < 128 * 32; i += 256) {
        int c = i & 127, d = (i >> 7) * 4;
        float w0 = Wg[(d + 0) * 128 + c];
        float w1 = Wg[(d + 1) * 128 + c];
        float w2 = Wg[(d + 2) * 128 + c];
        float w3 = Wg[(d + 3) * 128 + c];
        __half2 p0 = __floats2half2_rn(w0, w1);
        __half2 p1 = __floats2half2_rn(w2, w3);
        uint2 pk;
        pk.x = *(unsigned*)&p0;
        pk.y = *(unsigned*)&p1;
        *(uint2*)&Wt[c * 136 + d] = pk;
    }
    if (t < 128) { attS[t] = atts[t]; attD[t] = attd[t]; }
    __syncthreads();
    int wv = t >> 6, lane = t & 63;
    int m16 = lane & 15, quad = lane >> 4;
    int n0 = blockIdx.x * 64 + wv * 16;
    f32x4 acc[8];
    #pragma unroll
    for (int ct = 0; ct < 8; ct++) acc[ct] = (f32x4){0.f, 0.f, 0.f, 0.f};
    #pragma unroll
    for (int ks = 0; ks < 4; ks++) {
        int d0 = ks * 32 + quad * 8;
        half8 bf = *(const half8*)&h[(size_t)(n0 + m16) * 128 + d0];
        #pragma unroll
        for (int ct = 0; ct < 8; ct++) {
            half8 af = *(const half8*)&Wt[(ct * 16 + m16) * 136 + d0];
            acc[ct] = __builtin_amdgcn_mfma_f32_16x16x32_f16(af, bf, acc[ct], 0, 0, 0);
        }
    }
    __half* xrow = &x16[(size_t)(n0 + m16) * 128 + quad * 4];
    float ps[4] = {0.f, 0.f, 0.f, 0.f}, pd[4] = {0.f, 0.f, 0.f, 0.f};
    #pragma unroll
    for (int ct = 0; ct < 8; ct++) {
        f32x4 a = acc[ct];
        __half2 h0p = __floats2half2_rn(a[0], a[1]);
        __half2 h1p = __floats2half2_rn(a[2], a[3]);
        uint2 pk;
        pk.x = *(unsigned*)&h0p;
        pk.y = *(unsigned*)&h1p;
        *(uint2*)&xrow[ct * 16] = pk;
        int cb = ct * 16 + quad * 4;
        int hh = ct >> 1;
        ps[hh] += a[0] * attS[cb] + a[1] * attS[cb + 1]
                + a[2] * attS[cb + 2] + a[3] * attS[cb + 3];
        pd[hh] += a[0] * attD[cb] + a[1] * attD[cb + 1]
                + a[2] * attD[cb + 2] + a[3] * attD[cb + 3];
    }
    #pragma unroll
    for (int hh = 0; hh < 4; hh++) {
        ps[hh] += __shfl_xor(ps[hh], 16, 64);
        ps[hh] += __shfl_xor(ps[hh], 32, 64);
        pd[hh] += __shfl_xor(pd[hh], 16, 64);
        pd[hh] += __shfl_xor(pd[hh], 32, 64);
    }
    if (lane < 16) {
        int n = n0 + m16;
        *(float4*)&asd[(size_t)n * 8]     = make_float4(ps[0], ps[1], ps[2], ps[3]);
        *(float4*)&asd[(size_t)n * 8 + 4] = make_float4(pd[0], pd[1], pd[2], pd[3]);
    }
}

// ---------------------------------------------------------------------------
// K8a (k_zm FUSED): layer-1 aggregation (16-lane group/node, unroll 4) THEN
// the blockdiag-W1 MFMA in the same block (zs LDS tile + k_zm epilogue).
// ---------------------------------------------------------------------------
__global__ __launch_bounds__(256) void k_aggz(
    const int* __restrict__ offA, const int* __restrict__ offE,
    const unsigned* __restrict__ e4, const float* __restrict__ wb,
    const __half* __restrict__ h016, const __half* __restrict__ w1h,
    const float* __restrict__ b1, __half* __restrict__ hbuf)
{
    __shared__ __half Wt[128 * 40];     // 10240 B, [c*40+k]
    __shared__ __half zs[16][136];      // 4352 B, padded rows
    int t = threadIdx.x;
    {
        uint4* dst = (uint4*)Wt;
        const uint4* src = (const uint4*)w1h;
        for (int i = t; i < 640; i += 256) dst[i] = src[i];
    }
    int wv = t >> 6, lane = t & 63;
    int g = lane >> 4, q = lane & 15;
    int n = blockIdx.x * 16 + wv * 4 + g;        // grid exact: NN/16
    int beg = offA[n], end = offE[n];
    const __half2* x2 = (const __half2*)h016;
    float a0x = 0.f, a0y = 0.f, a1x = 0.f, a1y = 0.f;
    float a2x = 0.f, a2y = 0.f, a3x = 0.f, a3y = 0.f;
    float l0 = 0.f, l1 = 0.f, l2 = 0.f, l3 = 0.f;
    int i = beg;
    for (; i + 3 < end; i += 4) {
        unsigned u0 = e4[i],     u1 = e4[i + 1];
        unsigned u2 = e4[i + 2], u3 = e4[i + 3];
        float4 w0 = *(const float4*)&wb[(size_t)i * 4];
        float4 w1 = *(const float4*)&wb[(size_t)(i + 1) * 4];
        float4 w2 = *(const float4*)&wb[(size_t)(i + 2) * 4];
        float4 w3 = *(const float4*)&wb[(size_t)(i + 3) * 4];
        float2 x0 = __half22float2(x2[(u0 >> 15) * 16u + q]);
        float2 x1 = __half22float2(x2[(u1 >> 15) * 16u + q]);
        float2 x2v = __half22float2(x2[(u2 >> 15) * 16u + q]);
        float2 x3 = __half22float2(x2[(u3 >> 15) * 16u + q]);
        a0x += w0.x * x0.x + w1.x * x1.x + w2.x * x2v.x + w3.x * x3.x;
        a0y += w0.x * x0.y + w1.x * x1.y + w2.x * x2v.y + w3.x * x3.y;
        a1x += w0.y * x0.x + w1.y * x1.x + w2.y * x2v.x + w3.y * x3.x;
        a1y += w0.y * x0.y + w1.y * x1.y + w2.y * x2v.y + w3.y * x3.y;
        a2x += w0.z * x0.x + w1.z * x1.x + w2.z * x2v.x + w3.z * x3.x;
        a2y += w0.z * x0.y + w1.z * x1.y + w2.z * x2v.y + w3.z * x3.y;
        a3x += w0.w * x0.x + w1.w * x1.x + w2.w * x2v.x + w3.w * x3.x;
        a3y += w0.w * x0.y + w1.w * x1.y + w2.w * x2v.y + w3.w * x3.y;
        l0 += (w0.x + w1.x) + (w2.x + w3.x);
        l1 += (w0.y + w1.y) + (w2.y + w3.y);
        l2 += (w0.z + w1.z) + (w2.z + w3.z);
        l3 += (w0.w + w1.w) + (w2.w + w3.w);
    }
    for (; i < end; i++) {
        unsigned u0 = e4[i];
        float4 w0 = *(const float4*)&wb[(size_t)i * 4];
        float2 x0 = __half22float2(x2[(u0 >> 15) * 16u + q]);
        a0x += w0.x * x0.x;  a0y += w0.x * x0.y;
        a1x += w0.y * x0.x;  a1y += w0.y * x0.y;
        a2x += w0.z * x0.x;  a2y += w0.z * x0.y;
        a3x += w0.w * x0.x;  a3y += w0.w * x0.y;
        l0 += w0.x; l1 += w0.y; l2 += w0.z; l3 += w0.w;
    }
    float i0v = 1.0f / (l0 + 1e-16f);
    float i1v = 1.0f / (l1 + 1e-16f);
    float i2v = 1.0f / (l2 + 1e-16f);
    float i3v = 1.0f / (l3 + 1e-16f);
    int nl = wv * 4 + g;
    *(__half2*)&zs[nl][     q * 2] = __floats2half2_rn(a0x * i0v, a0y * i0v);
    *(__half2*)&zs[nl][32 + q * 2] = __floats2half2_rn(a1x * i1v, a1y * i1v);
    *(__half2*)&zs[nl][64 + q * 2] = __floats2half2_rn(a2x * i2v, a2y * i2v);
    *(__half2*)&zs[nl][96 + q * 2] = __floats2half2_rn(a3x * i3v, a3y * i3v);
    __syncthreads();
    // MFMA: wave wv owns col-tiles {2wv, 2wv+1} (head wv) for all 16 rows.
    int m16 = lane & 15, quad = lane >> 4;
    half8 bf = *(const half8*)&zs[m16][wv * 32 + quad * 8];
    __half* orow = &hbuf[(size_t)(blockIdx.x * 16 + m16) * 128 + quad * 4];
    #pragma unroll
    for (int c2 = 0; c2 < 2; c2++) {
        int ct = wv * 2 + c2;
        half8 af = *(const half8*)&Wt[(ct * 16 + m16) * 40 + quad * 8];
        f32x4 acc = __builtin_amdgcn_mfma_f32_16x16x32_f16(
            af, bf, (f32x4){0.f, 0.f, 0.f, 0.f}, 0, 0, 0);
        int cb = ct * 16 + quad * 4;
        float4 bb = *(const float4*)&b1[cb];
        float r0 = acc[0] + bb.x;
        float r1 = acc[1] + bb.y;
        float r2 = acc[2] + bb.z;
        float r3 = acc[3] + bb.w;
        r0 = r0 > 0.f ? r0 : __expf(r0) - 1.0f;
        r1 = r1 > 0.f ? r1 : __expf(r1) - 1.0f;
        r2 = r2 > 0.f ? r2 : __expf(r2) - 1.0f;
        r3 = r3 > 0.f ? r3 : __expf(r3) - 1.0f;
        __half2 ha = __floats2half2_rn(r0, r1);
        __half2 hb = __floats2half2_rn(r2, r3);
        uint2 pk;
        pk.x = *(unsigned*)&ha;
        pk.y = *(unsigned*)&hb;
        *(uint2*)&orow[ct * 16] = pk;
    }
}

// ---------------------------------------------------------------------------
// K8b: layer-2 aggregation with INLINE weight computation, UNROLL 4.
// 32-lane group per node.
// ---------------------------------------------------------------------------
__global__ __launch_bounds__(256) void k_agg2(
    const int* __restrict__ offA, const int* __restrict__ offE,
    const unsigned* __restrict__ e4,
    const float* __restrict__ lutg, const float* __restrict__ asd,
    const __half* __restrict__ x16, const float* __restrict__ bias,
    __half* __restrict__ hout)
{
    int t = threadIdx.x;
    int wv = t >> 6, lane = t & 63;
    int g = lane >> 5, q = lane & 31;
    int n = N_PRO + blockIdx.x * 8 + wv * 2 + g;  // grid exact: N_WAT/8
    int h = q >> 3;
    int beg = offA[n], end = offE[n];
    float adh = asd[(size_t)n * 8 + 4 + h];
    float ax = 0.f, ay = 0.f, az = 0.f, aw = 0.f, ls = 0.f;
    int i = beg;
    for (; i + 3 < end; i += 4) {
        unsigned uu[4];
        float ww[4];
        float2 rr[4];
        #pragma unroll
        for (int j = 0; j < 4; j++) uu[j] = e4[i + j];
        #pragma unroll
        for (int j = 0; j < 4; j++) {
            unsigned s = uu[j] >> 15;
            float f = fminf((float)(uu[j] & 32767u) * 0.0625f, (float)(LUTN - 2));
            int i0 = (int)f;
            float fr = f - (float)i0;
            float A = lutg[i0 * 4 + h], B = lutg[(i0 + 1) * 4 + h];
            float as0 = asd[(size_t)s * 8 + h];
            rr[j] = *(const float2*)&x16[(size_t)s * 128 + q * 4];
            float v = as0 + adh + A + (B - A) * fr;
            v = fmaxf(v, 0.2f * v);
            ww[j] = __expf(v);
        }
        #pragma unroll
        for (int j = 0; j < 4; j++) {
            float2 fa = __half22float2(*(__half2*)&rr[j].x);
            float2 fb = __half22float2(*(__half2*)&rr[j].y);
            ax += ww[j] * fa.x;
            ay += ww[j] * fa.y;
            az += ww[j] * fb.x;
            aw += ww[j] * fb.y;
            ls += ww[j];
        }
    }
    for (; i < end; i++) {
        unsigned u0 = e4[i];
        unsigned s0 = u0 >> 15;
        float f0 = fminf((float)(u0 & 32767u) * 0.0625f, (float)(LUTN - 2));
        int i00 = (int)f0;
        float fr0 = f0 - (float)i00;
        float A0 = lutg[i00 * 4 + h], B0 = lutg[(i00 + 1) * 4 + h];
        float as0 = asd[(size_t)s0 * 8 + h];
        float2 r0 = *(const float2*)&x16[(size_t)s0 * 128 + q * 4];
        float v0 = as0 + adh + A0 + (B0 - A0) * fr0;
        v0 = fmaxf(v0, 0.2f * v0);
        float w0 = __expf(v0);
        float2 f00 = __half22float2(*(__half2*)&r0.x);
        float2 f01 = __half22float2(*(__half2*)&r0.y);
        ax += w0 * f00.x; ay += w0 * f00.y;
        az += w0 * f01.x; aw += w0 * f01.y;
        ls += w0;
    }
    float inv = 1.0f / (ls + 1e-16f);
    float4 bb = *(const float4*)&bias[q * 4];
    float o0 = ax * inv + bb.x;
    float o1 = ay * inv + bb.y;
    float o2 = az * inv + bb.z;
    float o3 = aw * inv + bb.w;
    o0 = o0 > 0.f ? o0 : __expf(o0) - 1.0f;
    o1 = o1 > 0.f ? o1 : __expf(o1) - 1.0f;
    o2 = o2 > 0.f ? o2 : __expf(o2) - 1.0f;
    o3 = o3 > 0.f ? o3 : __expf(o3) - 1.0f;
    __half2 ha = __floats2half2_rn(o0, o1);
    __half2 hb = __floats2half2_rn(o2, o3);
    uint2 pk;
    pk.x = *(unsigned*)&ha;
    pk.y = *(unsigned*)&hb;
    *(uint2*)&hout[(size_t)n * 128 + q * 4] = pk;
}

// ---------------------------------------------------------------------------
// K9 (MFMA): water MLP, k_xm-structure. 64 nodes/block, Wm1^T fp16 in LDS,
// epilogue bias+ReLU then 128->2 layer-2 via per-lane dots + shuffle-reduce.
// ---------------------------------------------------------------------------
__global__ __launch_bounds__(256) void k_mlp(
    const __half* __restrict__ hh, const float* __restrict__ Wm1,
    const float* __restrict__ bm1, const float* __restrict__ Wm2,
    const float* __restrict__ bm2, float* __restrict__ out)
{
    __shared__ __half Wt[128 * 136];
    __shared__ float b1s[128];
    __shared__ float w2s[256];
    int t = threadIdx.x;
    for (int i = t; i < 128 * 32; i += 256) {
        int c = i & 127, d = (i >> 7) * 4;
        float w0 = Wm1[(d + 0) * 128 + c];
        float w1 = Wm1[(d + 1) * 128 + c];
        float w2 = Wm1[(d + 2) * 128 + c];
        float w3 = Wm1[(d + 3) * 128 + c];
        __half2 p0 = __floats2half2_rn(w0, w1);
        __half2 p1 = __floats2half2_rn(w2, w3);
        uint2 pk;
        pk.x = *(unsigned*)&p0;
        pk.y = *(unsigned*)&p1;
        *(uint2*)&Wt[c * 136 + d] = pk;
    }
    if (t < 128) b1s[t] = bm1[t];
    w2s[t] = Wm2[t];                       // 256 floats = [128][2]
    __syncthreads();
    int wv = t >> 6, lane = t & 63;
    int m16 = lane & 15, quad = lane >> 4;
    int n0 = blockIdx.x * 64 + wv * 16;    // water-local node base
    f32x4 acc[8];
    #pragma unroll
    for (int ct = 0; ct < 8; ct++) acc[ct] = (f32x4){0.f, 0.f, 0.f, 0.f};
    #pragma unroll
    for (int ks = 0; ks < 4; ks++) {
        int d0 = ks * 32 + quad * 8;
        half8 bf = *(const half8*)&hh[(size_t)(N_PRO + n0 + m16) * 128 + d0];
        #pragma unroll
        for (int ct = 0; ct < 8; ct++) {
            half8 af = *(const half8*)&Wt[(ct * 16 + m16) * 136 + d0];
            acc[ct] = __builtin_amdgcn_mfma_f32_16x16x32_f16(af, bf, acc[ct], 0, 0, 0);
        }
    }
    float p0 = 0.f, p1 = 0.f;
    #pragma unroll
    for (int ct = 0; ct < 8; ct++) {
        int cb = ct * 16 + quad * 4;
        float4 bb = *(const float4*)&b1s[cb];
        float r0 = fmaxf(acc[ct][0] + bb.x, 0.f);
        float r1 = fmaxf(acc[ct][1] + bb.y, 0.f);
        float r2 = fmaxf(acc[ct][2] + bb.z, 0.f);
        float r3 = fmaxf(acc[ct][3] + bb.w, 0.f);
        p0 += r0 * w2s[(cb + 0) * 2] + r1 * w2s[(cb + 1) * 2]
            + r2 * w2s[(cb + 2) * 2] + r3 * w2s[(cb + 3) * 2];
        p1 += r0 * w2s[(cb + 0) * 2 + 1] + r1 * w2s[(cb + 1) * 2 + 1]
            + r2 * w2s[(cb + 2) * 2 + 1] + r3 * w2s[(cb + 3) * 2 + 1];
    }
    p0 += __shfl_xor(p0, 16, 64);
    p0 += __shfl_xor(p0, 32, 64);
    p1 += __shfl_xor(p1, 16, 64);
    p1 += __shfl_xor(p1, 32, 64);
    if (lane < 16) {
        int wn = n0 + m16;
        *(float2*)&out[(size_t)wn * 2] = make_float2(p0 + bm2[0], p1 + bm2[1]);
    }
}

// ---------------------------------------------------------------------------
extern "C" void kernel_launch(void* const* d_in, const int* in_sizes, int n_in,
                              void* d_out, int out_size, void* d_ws, size_t ws_size,
                              hipStream_t stream)
{
    const float* ppos   = (const float*)d_in[0];
    const float* wpos   = (const float*)d_in[1];
    const float* pfeat  = (const float*)d_in[2];
    const int*   ei     = (const int*)d_in[3];
    const float* gamma  = (const float*)d_in[4];
    const float* Wf     = (const float*)d_in[5];
    const float* bfv    = (const float*)d_in[6];
    const float* We     = (const float*)d_in[7];
    const float* be     = (const float*)d_in[8];
    const float* W1     = (const float*)d_in[9];
    const float* atts1  = (const float*)d_in[10];
    const float* attd1  = (const float*)d_in[11];
    const float* Wedge1 = (const float*)d_in[12];
    const float* atte1  = (const float*)d_in[13];
    const float* b1     = (const float*)d_in[14];
    const float* W2     = (const float*)d_in[15];
    const float* atts2  = (const float*)d_in[16];
    const float* attd2  = (const float*)d_in[17];
    const float* Wedge2 = (const float*)d_in[18];
    const float* atte2  = (const float*)d_in[19];
    const float* b2     = (const float*)d_in[20];
    const float* Wm1    = (const float*)d_in[21];
    const float* bm1    = (const float*)d_in[22];
    const float* Wm2    = (const float*)d_in[23];
    const float* bm2    = (const float*)d_in[24];
    float* out = (float*)d_out;

    char* ws = (char*)d_ws;
    size_t o = 0;
    auto alloc = [&](size_t bytes) -> char* {
        char* p = ws + o;
        o += (bytes + 255) & ~(size_t)255;
        return p;
    };
    __half*   h0      = (__half*)alloc((size_t)NNP * 32 * 2);
    __half*   x16     = (__half*)alloc((size_t)NNP * 128 * 2);
    __half*   hbuf    = (__half*)alloc((size_t)NNP * 128 * 2);
    float*    asd     = (float*)alloc((size_t)NNP * 8 * 4);
    float*    wb      = (float*)alloc((size_t)SLOTS * 4 * 4);    // region-addressed
    int*      offA    = (int*)alloc((size_t)NN * 4);
    int*      offE    = (int*)alloc((size_t)NN * 4);
    unsigned* e4      = (unsigned*)alloc((size_t)SLOTS * 4);
    int*      gcur    = (int*)alloc((size_t)NBUCK * GSTRIDE * 4);
    float*    smallw  = (float*)alloc(4096);
    float*    lutbuf  = (float*)alloc((size_t)2 * LUTN * 4 * 4);
    __half*   w1h     = (__half*)alloc((size_t)128 * 40 * 2);
    // ebuf2 (9.6 MB) overlays hbuf (25.6 MB): written by k_hs (scat half),
    // last read by k_fine, strictly before hbuf's first write in k_aggz.
    uint2*    ebuf2   = (uint2*)hbuf;

    // 7 dispatches total.
    k_pre<<<17, 256, 0, stream>>>(We, be, Wedge1, atte1, Wedge2, atte2, Wf, bfv,
                                  W1, atts1, attd1, gamma,
                                  smallw, lutbuf, w1h, gcur);
    k_hs<<<SCATB + NH0B, HSTH, 0, stream>>>(pfeat, Wf, bfv, smallw, ei, ppos, wpos,
                                            gcur, ebuf2, h0, asd);
    k_fine<<<NBUCK, 1024, 0, stream>>>(gcur, ebuf2, lutbuf, asd, offA, offE, e4, wb);
    k_aggz<<<NN / 16, 256, 0, stream>>>(offA, offE, e4, wb, h0, w1h, b1, hbuf);
    k_xm<<<NNP / 64, 256, 0, stream>>>(hbuf, W2, atts2, attd2, x16, asd);
    k_agg2<<<N_WAT / 8, 256, 0, stream>>>(offA, offE, e4,
                                          lutbuf + (size_t)LUTN * 4, asd, x16, b2, hbuf);
    k_mlp<<<N_WAT / 64, 256, 0, stream>>>(hbuf, Wm1, bm1, Wm2, bm2, out);
}